// Round 6
// baseline (632.885 us; speedup 1.0000x reference)
//
#include <hip/hip_runtime.h>

#define NN 245760
#define NB 4096
#define NPER 60
#define NE 2000000
#define KSEL 30
#define NDRUG 1024
#define NDIS 2048
#define NBKT 480          // buckets of 512 nodes (NN = 480*512)
#define CHUNK 8192
#define SEGCAP 4992       // max edges per bucket (mean 4167, +12 sigma)

typedef unsigned short ushort_t;
typedef unsigned int uint_t;
using bf16x8 = __attribute__((ext_vector_type(8))) short;
using f32x4 = __attribute__((ext_vector_type(4))) float;

__device__ inline ushort_t f2bf(float f) {
    union { float f; unsigned int u; } v; v.f = f;
    unsigned int r = v.u + 0x7FFF + ((v.u >> 16) & 1);
    return (ushort_t)(r >> 16);
}

// ---------------- CSR build via bucketed 2-pass sort ----------------
__global__ void k_bcount(const int* __restrict__ ei, int* __restrict__ bcnt) {
    __shared__ int h[NBKT];
    int t = threadIdx.x;
    for (int i = t; i < NBKT; i += 256) h[i] = 0;
    __syncthreads();
    for (int e = blockIdx.x * 256 + t; e < NE; e += gridDim.x * 256)
        atomicAdd(&h[ei[NE + e] >> 9], 1);
    __syncthreads();
    for (int i = t; i < NBKT; i += 256) if (h[i]) atomicAdd(&bcnt[i], h[i]);
}

__global__ void k_bscan(const int* __restrict__ bcnt, int* __restrict__ bofs) {
    __shared__ int a[512], b_[512];
    int t = threadIdx.x;   // 512 threads
    int v = (t < NBKT) ? bcnt[t] : 0;
    a[t] = v; __syncthreads();
    int* src = a; int* dst = b_;
    for (int off = 1; off < 512; off <<= 1) {
        dst[t] = src[t] + ((t >= off) ? src[t - off] : 0);
        __syncthreads();
        int* tmp = src; src = dst; dst = tmp;
    }
    if (t < NBKT) bofs[t] = src[t] - v;   // exclusive
}

__global__ __launch_bounds__(256) void k_bscatter(const int* __restrict__ ei,
                                                  const int* __restrict__ bofs,
                                                  int* __restrict__ bfill,
                                                  uint_t* __restrict__ pairs) {
    __shared__ int hist[NBKT], fill[NBKT], gbase[NBKT];
    int t = threadIdx.x;
    long e0 = (long)blockIdx.x * CHUNK;
    int cnt = (int)min((long)CHUNK, (long)NE - e0);
    for (int i = t; i < NBKT; i += 256) { hist[i] = 0; fill[i] = 0; }
    __syncthreads();
    for (int i = t; i < cnt; i += 256)
        atomicAdd(&hist[ei[NE + e0 + i] >> 9], 1);
    __syncthreads();
    for (int i = t; i < NBKT; i += 256)
        if (hist[i]) gbase[i] = bofs[i] + atomicAdd(&bfill[i], hist[i]);
    __syncthreads();
    for (int i = t; i < cnt; i += 256) {
        int s = ei[e0 + i], d = ei[NE + e0 + i];
        int b = d >> 9;
        int pos = gbase[b] + atomicAdd(&fill[b], 1);
        pairs[pos] = ((uint_t)s << 9) | (uint_t)(d & 511);
    }
}

__global__ __launch_bounds__(256) void k_bbuild(const uint_t* __restrict__ pairs,
                                                const int* __restrict__ bofs,
                                                const int* __restrict__ bcnt,
                                                int* __restrict__ csr,
                                                int* __restrict__ rowp,
                                                int* __restrict__ cntg,
                                                float* __restrict__ dinv) {
    __shared__ int hist[512], nbase[512], nfill[512], scanA[512], scanB[512];
    __shared__ int seg[SEGCAP];
    int t = threadIdx.x, b = blockIdx.x;
    int ebase = bofs[b], ecnt = bcnt[b];
    if (ecnt > SEGCAP) ecnt = SEGCAP;
    for (int i = t; i < 512; i += 256) { hist[i] = 0; nfill[i] = 0; }
    __syncthreads();
    for (int i = t; i < ecnt; i += 256)
        atomicAdd(&hist[pairs[ebase + i] & 511], 1);
    __syncthreads();
    for (int i = t; i < 512; i += 256) scanA[i] = hist[i];
    __syncthreads();
    int* src = scanA; int* dst = scanB;
    for (int off = 1; off < 512; off <<= 1) {
        for (int i = t; i < 512; i += 256)
            dst[i] = src[i] + ((i >= off) ? src[i - off] : 0);
        __syncthreads();
        int* tmp = src; src = dst; dst = tmp;
    }
    for (int i = t; i < 512; i += 256) {
        int h = hist[i];
        int excl = src[i] - h;
        nbase[i] = excl;
        int n = (b << 9) + i;
        rowp[n] = ebase + excl;
        cntg[n] = h;
        dinv[n] = 1.0f / sqrtf((float)h + 1.0f);
    }
    __syncthreads();
    for (int i = t; i < ecnt; i += 256) {
        uint_t v = pairs[ebase + i];
        int ln = v & 511;
        int pos = nbase[ln] + atomicAdd(&nfill[ln], 1);
        if (pos < SEGCAP) seg[pos] = (int)(v >> 9);
    }
    __syncthreads();
    for (int i = t; i < ecnt; i += 256) csr[ebase + i] = seg[i];
}

// ---------------- X(M x K, stride lda) @ W(K x 32) -> h(M x 32), K<=64 ----------------
__global__ __launch_bounds__(256) void k_xw(const float* __restrict__ A, const float* __restrict__ W,
                                            float* __restrict__ h, int K, int lda) {
    __shared__ float Xs[64][65];
    __shared__ float Ws[64][32];
    int t = threadIdx.x;
    int r0 = blockIdx.x * 64;
    int kq = K >> 2;
    for (int idx = t; idx < 64 * kq; idx += 256) {
        int row = idx / kq, q = idx % kq;
        float4 v = *(const float4*)(A + (long)(r0 + row) * lda + q * 4);
        Xs[row][q * 4 + 0] = v.x; Xs[row][q * 4 + 1] = v.y;
        Xs[row][q * 4 + 2] = v.z; Xs[row][q * 4 + 3] = v.w;
    }
    for (int idx = t; idx < K * 32; idx += 256) ((float*)Ws)[idx] = W[idx];
    __syncthreads();
    int r = (t >> 3) * 2, c = (t & 7) * 4;
    float4 acc0 = {0, 0, 0, 0}, acc1 = {0, 0, 0, 0};
    for (int k = 0; k < K; k++) {
        float x0 = Xs[r][k], x1 = Xs[r + 1][k];
        float4 w = *(const float4*)&Ws[k][c];
        acc0.x += x0 * w.x; acc0.y += x0 * w.y; acc0.z += x0 * w.z; acc0.w += x0 * w.w;
        acc1.x += x1 * w.x; acc1.y += x1 * w.y; acc1.z += x1 * w.z; acc1.w += x1 * w.w;
    }
    *(float4*)(h + (long)(r0 + r) * 32 + c) = acc0;
    *(float4*)(h + (long)(r0 + r + 1) * 32 + c) = acc1;
}

__global__ void k_gcn_agg(const float* __restrict__ h, const int* __restrict__ csr,
                          const int* __restrict__ rowp, const int* __restrict__ cnt,
                          const float* __restrict__ dinv, const float* __restrict__ bias,
                          float* __restrict__ out, int colofs) {
    int t = threadIdx.x;
    int l = t & 7, g = t >> 3;
    int d = blockIdx.x * 32 + g;
    float dd = dinv[d];
    int start = rowp[d], c = cnt[d];
    float4 hv = *(const float4*)(h + (long)d * 32 + l * 4);
    float4 acc; acc.x = dd * hv.x; acc.y = dd * hv.y; acc.z = dd * hv.z; acc.w = dd * hv.w;
    for (int k = 0; k < c; k++) {
        int s = csr[start + k];
        float ds = dinv[s];
        float4 v = *(const float4*)(h + (long)s * 32 + l * 4);
        acc.x += ds * v.x; acc.y += ds * v.y; acc.z += ds * v.z; acc.w += ds * v.w;
    }
    float4 bv = *(const float4*)(bias + l * 4);
    float* op = out + (long)d * 64 + colofs + l * 4;
    op[0] = fmaxf(dd * acc.x + bv.x, 0.f);
    op[1] = fmaxf(dd * acc.y + bv.y, 0.f);
    op[2] = fmaxf(dd * acc.z + bv.z, 0.f);
    op[3] = fmaxf(dd * acc.w + bv.w, 0.f);
}

// ---------------- conv2: bf16 MFMA im2col GEMM ----------------
__global__ __launch_bounds__(256, 2) void k_conv2_mfma(const ushort_t* __restrict__ pool16,
                                                       const ushort_t* __restrict__ w2colT,
                                                       ushort_t* __restrict__ act2,
                                                       const float* __restrict__ bias) {
    __shared__ ushort_t A_lds[128 * 72];
    __shared__ ushort_t B_lds[128 * 72];
    int t = threadIdx.x;
    int r0 = blockIdx.x * 128, c0 = blockIdx.y * 128;
    long abase[4]; const ushort_t* bptr[4]; int lofs[4];
#pragma unroll
    for (int rnd = 0; rnd < 4; rnd++) {
        int idx = t + rnd * 256;
        int row = idx >> 3, seg = idx & 7;
        int arow = r0 + row;
        int bb = arow / 11, tt2 = arow - bb * 11;
        abase[rnd] = (long)(bb * 15 + tt2) * 128 + seg * 8;
        bptr[rnd] = w2colT + (long)(c0 + row) * 640 + seg * 8;
        lofs[rnd] = row * 72 + seg * 8;
    }
    int wv = t >> 6, lane = t & 63;
    int wm = wv >> 1, wn = wv & 1;
    int lrow = lane & 15, lk = (lane >> 4) * 8, lr4 = (lane >> 4) * 4;
    f32x4 acc[4][4] = {};
    for (int k0 = 0; k0 < 640; k0 += 64) {
#pragma unroll
        for (int rnd = 0; rnd < 4; rnd++) {
            *(uint4*)&A_lds[lofs[rnd]] = *(const uint4*)(pool16 + abase[rnd] + k0);
            *(uint4*)&B_lds[lofs[rnd]] = *(const uint4*)(bptr[rnd] + k0);
        }
        __syncthreads();
#pragma unroll
        for (int kk = 0; kk < 2; kk++) {
            bf16x8 a[4], b[4];
#pragma unroll
            for (int f = 0; f < 4; f++) {
                a[f] = *(const bf16x8*)&A_lds[(wm * 64 + f * 16 + lrow) * 72 + kk * 32 + lk];
                b[f] = *(const bf16x8*)&B_lds[(wn * 64 + f * 16 + lrow) * 72 + kk * 32 + lk];
            }
#pragma unroll
            for (int i = 0; i < 4; i++)
#pragma unroll
                for (int j = 0; j < 4; j++)
                    acc[i][j] = __builtin_amdgcn_mfma_f32_16x16x32_bf16(a[i], b[j], acc[i][j], 0, 0, 0);
        }
        __syncthreads();
    }
#pragma unroll
    for (int fn = 0; fn < 4; fn++) {
        int col = c0 + wn * 64 + fn * 16 + lrow;
        float bv = bias[col];
#pragma unroll
        for (int fm = 0; fm < 4; fm++) {
            int rowb = r0 + wm * 64 + fm * 16 + lr4;
#pragma unroll
            for (int j = 0; j < 4; j++)
                act2[(long)(rowb + j) * 256 + col] = f2bf(fmaxf(acc[fm][fn][j] + bv, 0.f));
        }
    }
}

// ---------------- lin1: bf16 MFMA split-K, fp32 atomic epilogue ----------------
__global__ __launch_bounds__(256, 2) void k_lin1_mfma(const ushort_t* __restrict__ A,
                                                      const ushort_t* __restrict__ Bm,
                                                      float* __restrict__ C) {
    __shared__ ushort_t A_lds[128 * 72];
    __shared__ ushort_t B_lds[128 * 72];
    int t = threadIdx.x;
    int r0 = blockIdx.x * 128;
    int kz = blockIdx.z;
    const ushort_t* ap[4]; const ushort_t* bp[4]; int lofs[4];
#pragma unroll
    for (int rnd = 0; rnd < 4; rnd++) {
        int idx = t + rnd * 256;
        int row = idx >> 3, seg = idx & 7;
        ap[rnd] = A + (long)(r0 + row) * 2816 + kz * 704 + seg * 8;
        bp[rnd] = Bm + (long)row * 2816 + kz * 704 + seg * 8;
        lofs[rnd] = row * 72 + seg * 8;
    }
    int wv = t >> 6, lane = t & 63;
    int wm = wv >> 1, wn = wv & 1;
    int lrow = lane & 15, lk = (lane >> 4) * 8, lr4 = (lane >> 4) * 4;
    f32x4 acc[4][4] = {};
    for (int k0 = 0; k0 < 704; k0 += 64) {
#pragma unroll
        for (int rnd = 0; rnd < 4; rnd++) {
            *(uint4*)&A_lds[lofs[rnd]] = *(const uint4*)(ap[rnd] + k0);
            *(uint4*)&B_lds[lofs[rnd]] = *(const uint4*)(bp[rnd] + k0);
        }
        __syncthreads();
#pragma unroll
        for (int kk = 0; kk < 2; kk++) {
            bf16x8 a[4], b[4];
#pragma unroll
            for (int f = 0; f < 4; f++) {
                a[f] = *(const bf16x8*)&A_lds[(wm * 64 + f * 16 + lrow) * 72 + kk * 32 + lk];
                b[f] = *(const bf16x8*)&B_lds[(wn * 64 + f * 16 + lrow) * 72 + kk * 32 + lk];
            }
#pragma unroll
            for (int i = 0; i < 4; i++)
#pragma unroll
                for (int j = 0; j < 4; j++)
                    acc[i][j] = __builtin_amdgcn_mfma_f32_16x16x32_bf16(a[i], b[j], acc[i][j], 0, 0, 0);
        }
        __syncthreads();
    }
#pragma unroll
    for (int fn = 0; fn < 4; fn++) {
        int col = wn * 64 + fn * 16 + lrow;
#pragma unroll
        for (int fm = 0; fm < 4; fm++) {
            int rowb = r0 + wm * 64 + fm * 16 + lr4;
#pragma unroll
            for (int j = 0; j < 4; j++)
                atomicAdd(&C[(long)(rowb + j) * 128 + col], acc[fm][fn][j]);
        }
    }
}

// ---------------- dual-problem split-K 64x64 GEMM (fp32, dense paths) ----------------
__global__ __launch_bounds__(256) void k_gemm_sk(
    const float* A0, const float* B0, float* C0, const float* ab0p, const float* cs0p,
    int M0, int N0, int K0, int lda0, int KS0, int Kc0,
    const float* A1, const float* B1, float* C1, const float* ab1p, const float* cs1p,
    int M1, int N1, int K1, int lda1, int KS1, int Kc1) {
    int z = blockIdx.z;
    const float* A; const float* Bm; float* C; const float* abp; const float* csp;
    int M, N, K, lda, kz, Kc;
    if (z < KS0) { A = A0; Bm = B0; C = C0; abp = ab0p; csp = cs0p; M = M0; N = N0; K = K0; lda = lda0; kz = z; Kc = Kc0; }
    else { A = A1; Bm = B1; C = C1; abp = ab1p; csp = cs1p; M = M1; N = N1; K = K1; lda = lda1; kz = z - KS0; Kc = Kc1; }
    int r0 = blockIdx.x * 64, c0 = blockIdx.y * 64;
    if (r0 >= M || c0 >= N) return;
    int kb = kz * Kc, ke = min(K, kb + Kc);
    __shared__ float As[16][68];
    __shared__ float Bs[16][68];
    int t = threadIdx.x;
    int tx = t & 15, ty = t >> 4;
    float acc[4][4] = {};
    int ar = t >> 2, aq = (t & 3) * 4;
    long abase = (long)(r0 + ar) * lda;
    int brow = t >> 4, bc = (t & 15) * 4;
    for (int k0 = kb; k0 < ke; k0 += 16) {
        float4 av = *(const float4*)(A + abase + k0 + aq);
        if (abp) {
            float4 abv = *(const float4*)(abp + k0 + aq);
            av.x += abv.x; av.y += abv.y; av.z += abv.z; av.w += abv.w;
        }
        As[aq + 0][ar] = av.x; As[aq + 1][ar] = av.y; As[aq + 2][ar] = av.z; As[aq + 3][ar] = av.w;
        float4 bv = *(const float4*)(Bm + (long)(k0 + brow) * N + c0 + bc);
        *(float4*)&Bs[brow][bc] = bv;
        __syncthreads();
#pragma unroll
        for (int kk = 0; kk < 16; kk++) {
            float4 a4 = *(const float4*)&As[kk][ty * 4];
            float4 b4 = *(const float4*)&Bs[kk][tx * 4];
            float aa[4] = {a4.x, a4.y, a4.z, a4.w};
            float bb2[4] = {b4.x, b4.y, b4.z, b4.w};
#pragma unroll
            for (int i = 0; i < 4; i++)
#pragma unroll
                for (int j = 0; j < 4; j++) acc[i][j] += aa[i] * bb2[j];
        }
        __syncthreads();
    }
#pragma unroll
    for (int i = 0; i < 4; i++) {
        int row = r0 + ty * 4 + i;
        float sc = csp ? csp[row] : 1.0f;
#pragma unroll
        for (int j = 0; j < 4; j++)
            atomicAdd(&C[(long)row * N + c0 + tx * 4 + j], acc[i][j] * sc);
    }
}

// ---------------- dense-path fused pieces ----------------
__global__ void k_dense_deg2(const float* __restrict__ adj0, float* __restrict__ d0, int n0,
                             const float* __restrict__ adj1, float* __restrict__ d1, int n1) {
    int lane = threadIdx.x & 63;
    int row = (blockIdx.x * blockDim.x + threadIdx.x) >> 6;
    const float* adj; float* dv; int n, r;
    if (row < n0) { adj = adj0; dv = d0; n = n0; r = row; }
    else {
        r = row - n0;
        if (r >= n1) return;
        adj = adj1; dv = d1; n = n1;
    }
    const float* rp = adj + (long)r * n;
    float s = 0.f;
    for (int j = lane; j < n; j += 64) s += rp[j];
    for (int off = 32; off > 0; off >>= 1) s += __shfl_down(s, off, 64);
    if (lane == 0) {
        float deg = s - rp[r] + 1.0f;
        dv[r] = (deg > 0.f) ? 1.0f / sqrtf(deg) : 0.f;
    }
}

__global__ void k_fix_w4(const float* g0, const float* u0, const float* adj0, const float* d0, float* o0, int n0,
                         const float* g1, const float* u1, const float* adj1, const float* d1, float* o1, int n1,
                         const float* __restrict__ b3, const float* __restrict__ W4) {
    __shared__ float dfs[16][68];
    __shared__ float W4s[64 * 16];
    int t = threadIdx.x;
    for (int i = t; i < 1024; i += 256) W4s[i] = W4[i];
    int bx = blockIdx.x, nb0 = n0 / 16;
    const float* g; const float* u; const float* adj; const float* dv; float* o; int n, r0;
    if (bx < nb0) { g = g0; u = u0; adj = adj0; dv = d0; o = o0; n = n0; r0 = bx * 16; }
    else { g = g1; u = u1; adj = adj1; dv = d1; o = o1; n = n1; r0 = (bx - nb0) * 16; }
    int r = t >> 4;
    int row = r0 + r;
    float di = dv[row];
    float om = 1.0f - adj[(long)row * n + row];
    int c4 = (t & 15) * 4;
    float4 gv = *(const float4*)(g + (long)row * 64 + c4);
    float4 uv = *(const float4*)(u + (long)row * 64 + c4);
    float4 bv = *(const float4*)(b3 + c4);
    dfs[r][c4 + 0] = fmaxf(di * (gv.x + om * uv.x) + bv.x, 0.f);
    dfs[r][c4 + 1] = fmaxf(di * (gv.y + om * uv.y) + bv.y, 0.f);
    dfs[r][c4 + 2] = fmaxf(di * (gv.z + om * uv.z) + bv.z, 0.f);
    dfs[r][c4 + 3] = fmaxf(di * (gv.w + om * uv.w) + bv.w, 0.f);
    __syncthreads();
    int c = t & 15;
    float accv = 0.f;
#pragma unroll
    for (int k = 0; k < 64; k++) accv += dfs[r][k] * W4s[k * 16 + c];
    o[row * 16 + c] = di * accv;
}

__global__ void k_fixup2(const float* g0, const float* t0, const float* adj0, const float* d0, float* C0, long n0,
                         const float* g1, const float* t1, const float* adj1, const float* d1, float* C1, long n1,
                         const float* bias, int cols) {
    long idx = (long)blockIdx.x * 256 + threadIdx.x;
    long s0 = n0 * cols;
    const float* g; const float* tt; const float* adj; const float* dv; float* C; long n, li;
    if (idx < s0) { g = g0; tt = t0; adj = adj0; dv = d0; C = C0; n = n0; li = idx; }
    else {
        li = idx - s0;
        if (li >= n1 * cols) return;
        g = g1; tt = t1; adj = adj1; dv = d1; C = C1; n = n1;
    }
    long i = li / cols; int j = li % cols;
    float v = dv[i] * (g[li] + (1.0f - adj[i * n + i]) * tt[li]) + bias[j];
    C[li] = fmaxf(v, 0.f);
}

__global__ void k_adj16(const float* adj0, const float* u0, float* C0, int n0, int KS0, int Kc0,
                        const float* adj1, const float* u1, float* C1, int n1, int KS1, int Kc1) {
    int z = blockIdx.z;
    const float* adj; const float* u; float* C; int n, kz, Kc;
    if (z < KS0) { adj = adj0; u = u0; C = C0; n = n0; kz = z; Kc = Kc0; }
    else { adj = adj1; u = u1; C = C1; n = n1; kz = z - KS0; Kc = Kc1; }
    int r0 = blockIdx.x * 16;
    if (r0 >= n) return;
    int t = threadIdx.x;
    int r = r0 + (t >> 4), c = t & 15;
    int kb = kz * Kc, ke = min(n, kb + Kc);
    const float* arp = adj + (long)r * n;
    float acc = 0.f;
    for (int k = kb; k < ke; k += 4) {
        float4 a = *(const float4*)(arp + k);
        acc += a.x * u[(k + 0) * 16 + c] + a.y * u[(k + 1) * 16 + c]
             + a.z * u[(k + 2) * 16 + c] + a.w * u[(k + 3) * 16 + c];
    }
    atomicAdd(&C[r * 16 + c], acc);
}

// ---------------- stable top-K selection ----------------
__global__ void k_select(const float* __restrict__ cs, int* __restrict__ sel) {
    __shared__ float kk[240];
    int t = threadIdx.x;
    int b0 = blockIdx.x * 4;
    if (t < 240) kk[t] = cs[((long)(b0 * 60 + t)) * 64 + 63];
    __syncthreads();
    if (t < 240) {
        int lb = t / 60, i = t % 60;
        float key = kk[lb * 60 + i];
        int r = 0;
        for (int j = 0; j < 60; j++) {
            float kj = kk[lb * 60 + j];
            r += (kj > key) || (kj == key && j < i);
        }
        if (r < KSEL) sel[(b0 + lb) * KSEL + r] = (b0 + lb) * 60 + i;
    }
}

// ---------------- conv1 + relu + maxpool2 -> bf16 pool (LDS-staged coalesced flush) ----------------
__global__ __launch_bounds__(256) void k_conv1_pool(const float* __restrict__ cs, const int* __restrict__ sel,
                                                    const float* __restrict__ c1w, const float* __restrict__ c1b,
                                                    ushort_t* __restrict__ po16) {
    __shared__ float4 xs4[30 * 16];
    __shared__ float4 w4[16][4][32];
    __shared__ ushort_t po[15 * 128];
    int t = threadIdx.x, b = blockIdx.x;
    for (int idx = t; idx < 480; idx += 256) {
        int i = idx >> 4, q = idx & 15;
        xs4[idx] = ((const float4*)(cs + (long)sel[b * KSEL + i] * 64))[q];
    }
    for (int idx = t; idx < 2048; idx += 256) {
        int oc = idx >> 4, tt4 = idx & 15;
        w4[tt4][oc & 3][oc >> 2] = ((const float4*)(c1w + oc * 64))[tt4];
    }
    __syncthreads();
    int g = t & 31;
    int kq = t >> 5;
    int k0 = kq * 4;
    int nk = (kq < 7) ? 4 : 2;
    float acc[4][4] = {};
    for (int tt4 = 0; tt4 < 16; tt4++) {
        float4 wv0 = w4[tt4][0][g], wv1 = w4[tt4][1][g];
        float4 wv2 = w4[tt4][2][g], wv3 = w4[tt4][3][g];
#pragma unroll
        for (int k = 0; k < 4; k++) {
            if (k < nk) {
                float4 xv = xs4[(k0 + k) * 16 + tt4];
                acc[k][0] += wv0.x * xv.x + wv0.y * xv.y + wv0.z * xv.z + wv0.w * xv.w;
                acc[k][1] += wv1.x * xv.x + wv1.y * xv.y + wv1.z * xv.z + wv1.w * xv.w;
                acc[k][2] += wv2.x * xv.x + wv2.y * xv.y + wv2.z * xv.z + wv2.w * xv.w;
                acc[k][3] += wv3.x * xv.x + wv3.y * xv.y + wv3.z * xv.z + wv3.w * xv.w;
            }
        }
    }
    int npair = nk >> 1;
    for (int kp = 0; kp < npair; kp++) {
        int k2 = (k0 >> 1) + kp;
#pragma unroll
        for (int j = 0; j < 4; j++) {
            int oc = g * 4 + j;
            float bb = c1b[oc];
            float v0 = fmaxf(acc[2 * kp][j] + bb, 0.f);
            float v1 = fmaxf(acc[2 * kp + 1][j] + bb, 0.f);
            po[k2 * 128 + oc] = f2bf(fmaxf(v0, v1));
        }
    }
    __syncthreads();
    // coalesced flush: 240 x uint4 (16B per lane, full-line coverage)
    uint4* dst = (uint4*)(po16 + (long)b * 1920);
    const uint4* srcp = (const uint4*)po;
    for (int i = t; i < 240; i += 256) dst[i] = srcp[i];
}

// ---------------- weight prep (bf16, transposed [out][k]) ----------------
__global__ void k_w2colT(const float* __restrict__ c2w, ushort_t* __restrict__ o) {
    int idx = blockIdx.x * blockDim.x + threadIdx.x;
    if (idx >= 256 * 640) return;
    int oc = idx / 640, q = idx % 640;
    int tap = q >> 7, ic = q & 127;
    o[idx] = f2bf(c2w[(oc * 128 + ic) * 5 + tap]);
}

__global__ void k_w1pT(const float* __restrict__ w, ushort_t* __restrict__ o) {
    int idx = blockIdx.x * blockDim.x + threadIdx.x;
    if (idx >= 128 * 2816) return;
    int j = idx / 2816, c = idx % 2816;
    int tt = c >> 8, oc = c & 255;
    o[idx] = f2bf(w[(oc * 11 + tt) * 128 + j]);
}

// ---------------- lin2 + bn (lin1 bias + relu folded into load) ----------------
__global__ void k_lin2_bn(const float* __restrict__ x, const float* __restrict__ l1b,
                          const float* __restrict__ w,
                          const float* __restrict__ b, const float* __restrict__ g,
                          const float* __restrict__ bb, float* __restrict__ o) {
    int t = blockIdx.x * blockDim.x + threadIdx.x;
    int j = t & 31, bi = t >> 5;
    const float* xr = x + (long)bi * 128;
    float acc = b[j];
    for (int k = 0; k < 128; k++) acc += fmaxf(xr[k] + l1b[k], 0.f) * w[k * 32 + j];
    o[bi * 32 + j] = fmaxf(acc * g[j] + bb[j], 0.f);
}

// ---------------- final fused MLP ----------------
__global__ __launch_bounds__(256) void k_final(const float* __restrict__ hfin, const int* __restrict__ node,
                                               const float* __restrict__ dio, const float* __restrict__ dro,
                                               const float* __restrict__ pp,
                                               const float* __restrict__ fw, const float* __restrict__ fb,
                                               const float* __restrict__ f2w, const float* __restrict__ f2b,
                                               float* __restrict__ out) {
    __shared__ float w[64 * 32];
    __shared__ float w2[32];
    int t = threadIdx.x;
    for (int f = t; f < 2048; f += 256) w[f] = fw[f];
    if (t < 32) w2[t] = f2w[t];
    __syncthreads();
    int b = blockIdx.x * 256 + t;
    float p = *pp, q = 1.0f - p;
    float zin[64];
#pragma unroll
    for (int i = 0; i < 32; i++) zin[i] = hfin[b * 32 + i] * p;
    int n0 = node[b * 2], n1 = node[b * 2 + 1];
#pragma unroll
    for (int i = 0; i < 16; i++) zin[32 + i] = dio[n0 * 16 + i] * q;
#pragma unroll
    for (int i = 0; i < 16; i++) zin[48 + i] = dro[n1 * 16 + i] * q;
    float res = f2b[0];
    for (int j = 0; j < 32; j++) {
        float acc = fb[j];
#pragma unroll
        for (int i = 0; i < 64; i++) acc += zin[i] * w[i * 32 + j];
        res += fmaxf(acc, 0.f) * w2[j];
    }
    out[b] = res;
}

// ---------------- host ----------------
extern "C" void kernel_launch(void* const* d_in, const int* in_sizes, int n_in,
                              void* d_out, int out_size, void* d_ws, size_t ws_size,
                              hipStream_t stream) {
    const float* x        = (const float*)d_in[0];
    const int*   ei       = (const int*)d_in[1];
    const int*   node     = (const int*)d_in[3];
    const float* di_sim   = (const float*)d_in[4];
    const float* dr_sim   = (const float*)d_in[5];
    const float* drug_adj = (const float*)d_in[6];
    const float* dis_adj  = (const float*)d_in[7];
    const float* p        = (const float*)d_in[8];
    const float* W1 = (const float*)d_in[9],  *b1 = (const float*)d_in[10];
    const float* W2 = (const float*)d_in[11], *b2 = (const float*)d_in[12];
    const float* W3 = (const float*)d_in[13], *b3 = (const float*)d_in[14];
    const float* W4 = (const float*)d_in[15], *b4 = (const float*)d_in[16];
    const float* lin_di_w = (const float*)d_in[17], *lin_di_b = (const float*)d_in[18];
    const float* lin_dr_w = (const float*)d_in[19], *lin_dr_b = (const float*)d_in[20];
    const float* c1w = (const float*)d_in[21], *c1b = (const float*)d_in[22];
    const float* c2w = (const float*)d_in[23], *c2b = (const float*)d_in[24];
    const float* lin1w = (const float*)d_in[25], *lin1b = (const float*)d_in[26];
    const float* lin2w = (const float*)d_in[27], *lin2b = (const float*)d_in[28];
    const float* bng = (const float*)d_in[29], *bnb = (const float*)d_in[30];
    const float* fcsw = (const float*)d_in[31], *fcsb = (const float*)d_in[32];
    const float* fcs2w = (const float*)d_in[33], *fcs2b = (const float*)d_in[34];

    char* ws = (char*)d_ws;
    size_t o = 0;
    auto alloc = [&](size_t bytes) { size_t r = o; o += (bytes + 255) & ~(size_t)255; return r; };
    int*   csr     = (int*)(ws + alloc((size_t)NE * 4));
    int*   rowp    = (int*)(ws + alloc((size_t)NN * 4));
    int*   degcnt  = (int*)(ws + alloc((size_t)NN * 4));
    float* dinvn   = (float*)(ws + alloc((size_t)NN * 4));
    float* hbuf    = (float*)(ws + alloc((size_t)NN * 32 * 4));  // reused as pool16
    float* cs      = (float*)(ws + alloc((size_t)NN * 64 * 4));  // first 8MB reused as pairs; later act2
    int*   sel     = (int*)(ws + alloc((size_t)NB * KSEL * 4));
    float* hfin    = (float*)(ws + alloc((size_t)NB * 32 * 4));
    ushort_t* w2colT = (ushort_t*)(ws + alloc((size_t)256 * 640 * 2));
    ushort_t* w1pT   = (ushort_t*)(ws + alloc((size_t)128 * 2816 * 2));
    int*   bofs    = (int*)(ws + alloc((size_t)NBKT * 4));
    float* ddin_di = (float*)(ws + alloc((size_t)NDRUG * 4));
    float* ddin_dr = (float*)(ws + alloc((size_t)NDIS * 4));
    float* dt2_di  = (float*)(ws + alloc((size_t)NDRUG * 16 * 4));
    float* dt2_dr  = (float*)(ws + alloc((size_t)NDIS * 16 * 4));
    float* do_di   = (float*)(ws + alloc((size_t)NDRUG * 16 * 4));
    float* do_dr   = (float*)(ws + alloc((size_t)NDIS * 16 * 4));
    size_t zbase = o;
    int*   bcnt    = (int*)(ws + alloc((size_t)NBKT * 4));
    int*   bfill   = (int*)(ws + alloc((size_t)NBKT * 4));
    float* lin1o   = (float*)(ws + alloc((size_t)NB * 128 * 4));
    float* de_di   = (float*)(ws + alloc((size_t)NDRUG * 256 * 4));
    float* de_dr   = (float*)(ws + alloc((size_t)NDIS * 256 * 4));
    float* dt_di   = (float*)(ws + alloc((size_t)NDRUG * 64 * 4));
    float* dt_dr   = (float*)(ws + alloc((size_t)NDIS * 64 * 4));
    float* dg_di   = (float*)(ws + alloc((size_t)NDRUG * 64 * 4));
    float* dg_dr   = (float*)(ws + alloc((size_t)NDIS * 64 * 4));
    float* dg2_di  = (float*)(ws + alloc((size_t)NDRUG * 16 * 4));
    float* dg2_dr  = (float*)(ws + alloc((size_t)NDIS * 16 * 4));
    size_t zsize = o - zbase;
    uint_t* pairsg   = (uint_t*)cs;       // 8MB scratch, dead before cs is written
    ushort_t* pool16 = (ushort_t*)hbuf;   // alias after GCN done
    ushort_t* act2   = (ushort_t*)cs;     // alias after conv1 done

    hipMemsetAsync(ws + zbase, 0, zsize, stream);

    // CSR build: bucketed 2-pass sort
    k_bcount<<<512, 256, 0, stream>>>(ei, bcnt);
    k_bscan<<<1, 512, 0, stream>>>(bcnt, bofs);
    k_bscatter<<<(NE + CHUNK - 1) / CHUNK, 256, 0, stream>>>(ei, bofs, bfill, pairsg);
    k_bbuild<<<NBKT, 256, 0, stream>>>(pairsg, bofs, bcnt, csr, rowp, degcnt, dinvn);

    // GCN (fp32 — preserves stable sort keys)
    k_xw<<<NN / 64, 256, 0, stream>>>(x, W1, hbuf, 64, 64);
    k_gcn_agg<<<NN / 32, 256, 0, stream>>>(hbuf, csr, rowp, degcnt, dinvn, b1, cs, 0);
    k_xw<<<NN / 64, 256, 0, stream>>>(cs, W2, hbuf, 32, 64);
    k_gcn_agg<<<NN / 32, 256, 0, stream>>>(hbuf, csr, rowp, degcnt, dinvn, b2, cs, 32);

    k_select<<<NB / 4, 256, 0, stream>>>(cs, sel);

    // weight prep (bf16 transposed)
    k_w2colT<<<(256 * 640 + 255) / 256, 256, 0, stream>>>(c2w, w2colT);
    k_w1pT<<<(128 * 2816 + 255) / 256, 256, 0, stream>>>(lin1w, w1pT);

    // conv1 + pool -> bf16 pool16 (aliases hbuf)
    k_conv1_pool<<<NB, 256, 0, stream>>>(cs, sel, c1w, c1b, pool16);

    // conv2: bf16 MFMA -> act2 bf16 (aliases cs)
    k_conv2_mfma<<<dim3(352, 2), 256, 0, stream>>>(pool16, w2colT, act2, c2b);

    // lin1: bf16 MFMA split-K -> lin1o fp32 (zeroed)
    k_lin1_mfma<<<dim3(32, 1, 4), 256, 0, stream>>>(act2, w1pT, lin1o);
    k_lin2_bn<<<NB * 32 / 256, 256, 0, stream>>>(lin1o, lin1b, lin2w, lin2b, bng, bnb, hfin);

    // ---- dense drug (p0) + disease (p1) paths (fp32) ----
    k_dense_deg2<<<(NDRUG + NDIS) * 64 / 256, 256, 0, stream>>>(drug_adj, ddin_di, NDRUG, dis_adj, ddin_dr, NDIS);
    k_gemm_sk<<<dim3(NDIS / 64, 4, 12), 256, 0, stream>>>(
        di_sim, lin_di_w, de_di, nullptr, nullptr, NDRUG, 256, NDRUG, NDRUG, 4, 256,
        dr_sim, lin_dr_w, de_dr, nullptr, nullptr, NDIS, 256, NDIS, NDIS, 8, 256);
    k_gemm_sk<<<dim3(NDIS / 64, 1, 8), 256, 0, stream>>>(
        de_di, W3, dt_di, lin_di_b, ddin_di, NDRUG, 64, 256, 256, 4, 64,
        de_dr, W3, dt_dr, lin_dr_b, ddin_dr, NDIS, 64, 256, 256, 4, 64);
    k_gemm_sk<<<dim3(NDIS / 64, 1, 24), 256, 0, stream>>>(
        drug_adj, dt_di, dg_di, nullptr, nullptr, NDRUG, 64, NDRUG, NDRUG, 8, 128,
        dis_adj, dt_dr, dg_dr, nullptr, nullptr, NDIS, 64, NDIS, NDIS, 16, 128);
    k_fix_w4<<<(NDRUG + NDIS) / 16, 256, 0, stream>>>(
        dg_di, dt_di, drug_adj, ddin_di, dt2_di, NDRUG,
        dg_dr, dt_dr, dis_adj, ddin_dr, dt2_dr, NDIS, b3, W4);
    k_adj16<<<dim3(NDIS / 16, 1, 6), 256, 0, stream>>>(
        drug_adj, dt2_di, dg2_di, NDRUG, 2, 512,
        dis_adj, dt2_dr, dg2_dr, NDIS, 4, 512);
    k_fixup2<<<((NDRUG + NDIS) * 16 + 255) / 256, 256, 0, stream>>>(
        dg2_di, dt2_di, drug_adj, ddin_di, do_di, NDRUG,
        dg2_dr, dt2_dr, dis_adj, ddin_dr, do_dr, NDIS, b4, 16);

    k_final<<<NB / 256, 256, 0, stream>>>(hfin, node, do_di, do_dr, p, fcsw, fcsb, fcs2w, fcs2b, (float*)d_out);
}

// Round 9
// 579.277 us; speedup vs baseline: 1.0925x; 1.0925x over previous
//
#include <hip/hip_runtime.h>

#define NN 245760
#define NB 4096
#define NPER 60
#define NE 2000000
#define KSEL 30
#define NDRUG 1024
#define NDIS 2048
#define NBKT 480          // buckets of 512 nodes (NN = 480*512)
#define CHUNK 8192
#define SEGCAP 4992       // max edges per bucket (mean 4167, +12 sigma)

typedef unsigned short ushort_t;
typedef unsigned int uint_t;
using bf16x8 = __attribute__((ext_vector_type(8))) short;
using f32x4 = __attribute__((ext_vector_type(4))) float;

__device__ inline ushort_t f2bf(float f) {
    union { float f; unsigned int u; } v; v.f = f;
    unsigned int r = v.u + 0x7FFF + ((v.u >> 16) & 1);
    return (ushort_t)(r >> 16);
}

// ---------------- CSR build via bucketed 2-pass sort ----------------
__global__ void k_bcount(const int* __restrict__ ei, int* __restrict__ bcnt) {
    __shared__ int h[NBKT];
    int t = threadIdx.x;
    for (int i = t; i < NBKT; i += 256) h[i] = 0;
    __syncthreads();
    for (int e = blockIdx.x * 256 + t; e < NE; e += gridDim.x * 256)
        atomicAdd(&h[ei[NE + e] >> 9], 1);
    __syncthreads();
    for (int i = t; i < NBKT; i += 256) if (h[i]) atomicAdd(&bcnt[i], h[i]);
}

__global__ void k_bscan(const int* __restrict__ bcnt, int* __restrict__ bofs) {
    __shared__ int a[512], b_[512];
    int t = threadIdx.x;   // 512 threads
    int v = (t < NBKT) ? bcnt[t] : 0;
    a[t] = v; __syncthreads();
    int* src = a; int* dst = b_;
    for (int off = 1; off < 512; off <<= 1) {
        dst[t] = src[t] + ((t >= off) ? src[t - off] : 0);
        __syncthreads();
        int* tmp = src; src = dst; dst = tmp;
    }
    if (t < NBKT) bofs[t] = src[t] - v;   // exclusive
}

__global__ __launch_bounds__(256) void k_bscatter(const int* __restrict__ ei,
                                                  const int* __restrict__ bofs,
                                                  int* __restrict__ bfill,
                                                  uint_t* __restrict__ pairs) {
    __shared__ int hist[NBKT], fill[NBKT], gbase[NBKT];
    int t = threadIdx.x;
    long e0 = (long)blockIdx.x * CHUNK;
    int cnt = (int)min((long)CHUNK, (long)NE - e0);
    for (int i = t; i < NBKT; i += 256) { hist[i] = 0; fill[i] = 0; }
    __syncthreads();
    for (int i = t; i < cnt; i += 256)
        atomicAdd(&hist[ei[NE + e0 + i] >> 9], 1);
    __syncthreads();
    for (int i = t; i < NBKT; i += 256)
        if (hist[i]) gbase[i] = bofs[i] + atomicAdd(&bfill[i], hist[i]);
    __syncthreads();
    for (int i = t; i < cnt; i += 256) {
        int s = ei[e0 + i], d = ei[NE + e0 + i];
        int b = d >> 9;
        int pos = gbase[b] + atomicAdd(&fill[b], 1);
        pairs[pos] = ((uint_t)s << 9) | (uint_t)(d & 511);
    }
}

__global__ __launch_bounds__(256) void k_bbuild(const uint_t* __restrict__ pairs,
                                                const int* __restrict__ bofs,
                                                const int* __restrict__ bcnt,
                                                int* __restrict__ csr,
                                                int* __restrict__ rowp,
                                                int* __restrict__ cntg,
                                                float* __restrict__ dinv) {
    __shared__ int hist[512], nbase[512], nfill[512], scanA[512], scanB[512];
    __shared__ int seg[SEGCAP];
    int t = threadIdx.x, b = blockIdx.x;
    int ebase = bofs[b], ecnt = bcnt[b];
    if (ecnt > SEGCAP) ecnt = SEGCAP;
    for (int i = t; i < 512; i += 256) { hist[i] = 0; nfill[i] = 0; }
    __syncthreads();
    for (int i = t; i < ecnt; i += 256)
        atomicAdd(&hist[pairs[ebase + i] & 511], 1);
    __syncthreads();
    for (int i = t; i < 512; i += 256) scanA[i] = hist[i];
    __syncthreads();
    int* src = scanA; int* dst = scanB;
    for (int off = 1; off < 512; off <<= 1) {
        for (int i = t; i < 512; i += 256)
            dst[i] = src[i] + ((i >= off) ? src[i - off] : 0);
        __syncthreads();
        int* tmp = src; src = dst; dst = tmp;
    }
    for (int i = t; i < 512; i += 256) {
        int h = hist[i];
        int excl = src[i] - h;
        nbase[i] = excl;
        int n = (b << 9) + i;
        rowp[n] = ebase + excl;
        cntg[n] = h;
        dinv[n] = 1.0f / sqrtf((float)h + 1.0f);
    }
    __syncthreads();
    for (int i = t; i < ecnt; i += 256) {
        uint_t v = pairs[ebase + i];
        int ln = v & 511;
        int pos = nbase[ln] + atomicAdd(&nfill[ln], 1);
        if (pos < SEGCAP) seg[pos] = (int)(v >> 9);
    }
    __syncthreads();
    for (int i = t; i < ecnt; i += 256) csr[ebase + i] = seg[i];
}

// ---------------- X(M x K, stride lda) @ W(K x 32) -> h(M x 32), K<=64 ----------------
__global__ __launch_bounds__(256) void k_xw(const float* __restrict__ A, const float* __restrict__ W,
                                            float* __restrict__ h, int K, int lda) {
    __shared__ float Xs[64][65];
    __shared__ float Ws[64][32];
    int t = threadIdx.x;
    int r0 = blockIdx.x * 64;
    int kq = K >> 2;
    for (int idx = t; idx < 64 * kq; idx += 256) {
        int row = idx / kq, q = idx % kq;
        float4 v = *(const float4*)(A + (long)(r0 + row) * lda + q * 4);
        Xs[row][q * 4 + 0] = v.x; Xs[row][q * 4 + 1] = v.y;
        Xs[row][q * 4 + 2] = v.z; Xs[row][q * 4 + 3] = v.w;
    }
    for (int idx = t; idx < K * 32; idx += 256) ((float*)Ws)[idx] = W[idx];
    __syncthreads();
    int r = (t >> 3) * 2, c = (t & 7) * 4;
    float4 acc0 = {0, 0, 0, 0}, acc1 = {0, 0, 0, 0};
    for (int k = 0; k < K; k++) {
        float x0 = Xs[r][k], x1 = Xs[r + 1][k];
        float4 w = *(const float4*)&Ws[k][c];
        acc0.x += x0 * w.x; acc0.y += x0 * w.y; acc0.z += x0 * w.z; acc0.w += x0 * w.w;
        acc1.x += x1 * w.x; acc1.y += x1 * w.y; acc1.z += x1 * w.z; acc1.w += x1 * w.w;
    }
    *(float4*)(h + (long)(r0 + r) * 32 + c) = acc0;
    *(float4*)(h + (long)(r0 + r + 1) * 32 + c) = acc1;
}

__global__ void k_gcn_agg(const float* __restrict__ h, const int* __restrict__ csr,
                          const int* __restrict__ rowp, const int* __restrict__ cnt,
                          const float* __restrict__ dinv, const float* __restrict__ bias,
                          float* __restrict__ out, int colofs) {
    int t = threadIdx.x;
    int l = t & 7, g = t >> 3;
    int d = blockIdx.x * 32 + g;
    float dd = dinv[d];
    int start = rowp[d], c = cnt[d];
    float4 hv = *(const float4*)(h + (long)d * 32 + l * 4);
    float4 acc; acc.x = dd * hv.x; acc.y = dd * hv.y; acc.z = dd * hv.z; acc.w = dd * hv.w;
    for (int k = 0; k < c; k++) {
        int s = csr[start + k];
        float ds = dinv[s];
        float4 v = *(const float4*)(h + (long)s * 32 + l * 4);
        acc.x += ds * v.x; acc.y += ds * v.y; acc.z += ds * v.z; acc.w += ds * v.w;
    }
    float4 bv = *(const float4*)(bias + l * 4);
    float* op = out + (long)d * 64 + colofs + l * 4;
    op[0] = fmaxf(dd * acc.x + bv.x, 0.f);
    op[1] = fmaxf(dd * acc.y + bv.y, 0.f);
    op[2] = fmaxf(dd * acc.z + bv.z, 0.f);
    op[3] = fmaxf(dd * acc.w + bv.w, 0.f);
}

// ---------------- conv2: bf16 MFMA im2col GEMM ----------------
__global__ __launch_bounds__(256, 2) void k_conv2_mfma(const ushort_t* __restrict__ pool16,
                                                       const ushort_t* __restrict__ w2colT,
                                                       ushort_t* __restrict__ act2,
                                                       const float* __restrict__ bias) {
    __shared__ ushort_t A_lds[128 * 72];
    __shared__ ushort_t B_lds[128 * 72];
    int t = threadIdx.x;
    int r0 = blockIdx.x * 128, c0 = blockIdx.y * 128;
    long abase[4]; const ushort_t* bptr[4]; int lofs[4];
#pragma unroll
    for (int rnd = 0; rnd < 4; rnd++) {
        int idx = t + rnd * 256;
        int row = idx >> 3, seg = idx & 7;
        int arow = r0 + row;
        int bb = arow / 11, tt2 = arow - bb * 11;
        abase[rnd] = (long)(bb * 15 + tt2) * 128 + seg * 8;
        bptr[rnd] = w2colT + (long)(c0 + row) * 640 + seg * 8;
        lofs[rnd] = row * 72 + seg * 8;
    }
    int wv = t >> 6, lane = t & 63;
    int wm = wv >> 1, wn = wv & 1;
    int lrow = lane & 15, lk = (lane >> 4) * 8, lr4 = (lane >> 4) * 4;
    f32x4 acc[4][4] = {};
    for (int k0 = 0; k0 < 640; k0 += 64) {
#pragma unroll
        for (int rnd = 0; rnd < 4; rnd++) {
            *(uint4*)&A_lds[lofs[rnd]] = *(const uint4*)(pool16 + abase[rnd] + k0);
            *(uint4*)&B_lds[lofs[rnd]] = *(const uint4*)(bptr[rnd] + k0);
        }
        __syncthreads();
#pragma unroll
        for (int kk = 0; kk < 2; kk++) {
            bf16x8 a[4], b[4];
#pragma unroll
            for (int f = 0; f < 4; f++) {
                a[f] = *(const bf16x8*)&A_lds[(wm * 64 + f * 16 + lrow) * 72 + kk * 32 + lk];
                b[f] = *(const bf16x8*)&B_lds[(wn * 64 + f * 16 + lrow) * 72 + kk * 32 + lk];
            }
#pragma unroll
            for (int i = 0; i < 4; i++)
#pragma unroll
                for (int j = 0; j < 4; j++)
                    acc[i][j] = __builtin_amdgcn_mfma_f32_16x16x32_bf16(a[i], b[j], acc[i][j], 0, 0, 0);
        }
        __syncthreads();
    }
#pragma unroll
    for (int fn = 0; fn < 4; fn++) {
        int col = c0 + wn * 64 + fn * 16 + lrow;
        float bv = bias[col];
#pragma unroll
        for (int fm = 0; fm < 4; fm++) {
            int rowb = r0 + wm * 64 + fm * 16 + lr4;
#pragma unroll
            for (int j = 0; j < 4; j++)
                act2[(long)(rowb + j) * 256 + col] = f2bf(fmaxf(acc[fm][fn][j] + bv, 0.f));
        }
    }
}

// ---------------- lin1: bf16 MFMA split-K, fp32 atomic epilogue ----------------
__global__ __launch_bounds__(256, 2) void k_lin1_mfma(const ushort_t* __restrict__ A,
                                                      const ushort_t* __restrict__ Bm,
                                                      float* __restrict__ C) {
    __shared__ ushort_t A_lds[128 * 72];
    __shared__ ushort_t B_lds[128 * 72];
    int t = threadIdx.x;
    int r0 = blockIdx.x * 128;
    int kz = blockIdx.z;
    const ushort_t* ap[4]; const ushort_t* bp[4]; int lofs[4];
#pragma unroll
    for (int rnd = 0; rnd < 4; rnd++) {
        int idx = t + rnd * 256;
        int row = idx >> 3, seg = idx & 7;
        ap[rnd] = A + (long)(r0 + row) * 2816 + kz * 704 + seg * 8;
        bp[rnd] = Bm + (long)row * 2816 + kz * 704 + seg * 8;
        lofs[rnd] = row * 72 + seg * 8;
    }
    int wv = t >> 6, lane = t & 63;
    int wm = wv >> 1, wn = wv & 1;
    int lrow = lane & 15, lk = (lane >> 4) * 8, lr4 = (lane >> 4) * 4;
    f32x4 acc[4][4] = {};
    for (int k0 = 0; k0 < 704; k0 += 64) {
#pragma unroll
        for (int rnd = 0; rnd < 4; rnd++) {
            *(uint4*)&A_lds[lofs[rnd]] = *(const uint4*)(ap[rnd] + k0);
            *(uint4*)&B_lds[lofs[rnd]] = *(const uint4*)(bp[rnd] + k0);
        }
        __syncthreads();
#pragma unroll
        for (int kk = 0; kk < 2; kk++) {
            bf16x8 a[4], b[4];
#pragma unroll
            for (int f = 0; f < 4; f++) {
                a[f] = *(const bf16x8*)&A_lds[(wm * 64 + f * 16 + lrow) * 72 + kk * 32 + lk];
                b[f] = *(const bf16x8*)&B_lds[(wn * 64 + f * 16 + lrow) * 72 + kk * 32 + lk];
            }
#pragma unroll
            for (int i = 0; i < 4; i++)
#pragma unroll
                for (int j = 0; j < 4; j++)
                    acc[i][j] = __builtin_amdgcn_mfma_f32_16x16x32_bf16(a[i], b[j], acc[i][j], 0, 0, 0);
        }
        __syncthreads();
    }
#pragma unroll
    for (int fn = 0; fn < 4; fn++) {
        int col = wn * 64 + fn * 16 + lrow;
#pragma unroll
        for (int fm = 0; fm < 4; fm++) {
            int rowb = r0 + wm * 64 + fm * 16 + lr4;
#pragma unroll
            for (int j = 0; j < 4; j++)
                atomicAdd(&C[(long)(rowb + j) * 128 + col], acc[fm][fn][j]);
        }
    }
}

// ---------------- dual-problem split-K 64x64 GEMM (fp32, dense paths) ----------------
__global__ __launch_bounds__(256) void k_gemm_sk(
    const float* A0, const float* B0, float* C0, const float* ab0p, const float* cs0p,
    int M0, int N0, int K0, int lda0, int KS0, int Kc0,
    const float* A1, const float* B1, float* C1, const float* ab1p, const float* cs1p,
    int M1, int N1, int K1, int lda1, int KS1, int Kc1) {
    int z = blockIdx.z;
    const float* A; const float* Bm; float* C; const float* abp; const float* csp;
    int M, N, K, lda, kz, Kc;
    if (z < KS0) { A = A0; Bm = B0; C = C0; abp = ab0p; csp = cs0p; M = M0; N = N0; K = K0; lda = lda0; kz = z; Kc = Kc0; }
    else { A = A1; Bm = B1; C = C1; abp = ab1p; csp = cs1p; M = M1; N = N1; K = K1; lda = lda1; kz = z - KS0; Kc = Kc1; }
    int r0 = blockIdx.x * 64, c0 = blockIdx.y * 64;
    if (r0 >= M || c0 >= N) return;
    int kb = kz * Kc, ke = min(K, kb + Kc);
    __shared__ float As[16][68];
    __shared__ float Bs[16][68];
    int t = threadIdx.x;
    int tx = t & 15, ty = t >> 4;
    float acc[4][4] = {};
    int ar = t >> 2, aq = (t & 3) * 4;
    long abase = (long)(r0 + ar) * lda;
    int brow = t >> 4, bc = (t & 15) * 4;
    for (int k0 = kb; k0 < ke; k0 += 16) {
        float4 av = *(const float4*)(A + abase + k0 + aq);
        if (abp) {
            float4 abv = *(const float4*)(abp + k0 + aq);
            av.x += abv.x; av.y += abv.y; av.z += abv.z; av.w += abv.w;
        }
        As[aq + 0][ar] = av.x; As[aq + 1][ar] = av.y; As[aq + 2][ar] = av.z; As[aq + 3][ar] = av.w;
        float4 bv = *(const float4*)(Bm + (long)(k0 + brow) * N + c0 + bc);
        *(float4*)&Bs[brow][bc] = bv;
        __syncthreads();
#pragma unroll
        for (int kk = 0; kk < 16; kk++) {
            float4 a4 = *(const float4*)&As[kk][ty * 4];
            float4 b4 = *(const float4*)&Bs[kk][tx * 4];
            float aa[4] = {a4.x, a4.y, a4.z, a4.w};
            float bb2[4] = {b4.x, b4.y, b4.z, b4.w};
#pragma unroll
            for (int i = 0; i < 4; i++)
#pragma unroll
                for (int j = 0; j < 4; j++) acc[i][j] += aa[i] * bb2[j];
        }
        __syncthreads();
    }
#pragma unroll
    for (int i = 0; i < 4; i++) {
        int row = r0 + ty * 4 + i;
        float sc = csp ? csp[row] : 1.0f;
#pragma unroll
        for (int j = 0; j < 4; j++)
            atomicAdd(&C[(long)row * N + c0 + tx * 4 + j], acc[i][j] * sc);
    }
}

// ---------------- dense-path fused pieces ----------------
__global__ void k_dense_deg2(const float* __restrict__ adj0, float* __restrict__ d0, int n0,
                             const float* __restrict__ adj1, float* __restrict__ d1, int n1) {
    int lane = threadIdx.x & 63;
    int row = (blockIdx.x * blockDim.x + threadIdx.x) >> 6;
    const float* adj; float* dv; int n, r;
    if (row < n0) { adj = adj0; dv = d0; n = n0; r = row; }
    else {
        r = row - n0;
        if (r >= n1) return;
        adj = adj1; dv = d1; n = n1;
    }
    const float* rp = adj + (long)r * n;
    float s = 0.f;
    for (int j = lane; j < n; j += 64) s += rp[j];
    for (int off = 32; off > 0; off >>= 1) s += __shfl_down(s, off, 64);
    if (lane == 0) {
        float deg = s - rp[r] + 1.0f;
        dv[r] = (deg > 0.f) ? 1.0f / sqrtf(deg) : 0.f;
    }
}

__global__ void k_fix_w4(const float* g0, const float* u0, const float* adj0, const float* d0, float* o0, int n0,
                         const float* g1, const float* u1, const float* adj1, const float* d1, float* o1, int n1,
                         const float* __restrict__ b3, const float* __restrict__ W4) {
    __shared__ float dfs[16][68];
    __shared__ float W4s[64 * 16];
    int t = threadIdx.x;
    for (int i = t; i < 1024; i += 256) W4s[i] = W4[i];
    int bx = blockIdx.x, nb0 = n0 / 16;
    const float* g; const float* u; const float* adj; const float* dv; float* o; int n, r0;
    if (bx < nb0) { g = g0; u = u0; adj = adj0; dv = d0; o = o0; n = n0; r0 = bx * 16; }
    else { g = g1; u = u1; adj = adj1; dv = d1; o = o1; n = n1; r0 = (bx - nb0) * 16; }
    int r = t >> 4;
    int row = r0 + r;
    float di = dv[row];
    float om = 1.0f - adj[(long)row * n + row];
    int c4 = (t & 15) * 4;
    float4 gv = *(const float4*)(g + (long)row * 64 + c4);
    float4 uv = *(const float4*)(u + (long)row * 64 + c4);
    float4 bv = *(const float4*)(b3 + c4);
    dfs[r][c4 + 0] = fmaxf(di * (gv.x + om * uv.x) + bv.x, 0.f);
    dfs[r][c4 + 1] = fmaxf(di * (gv.y + om * uv.y) + bv.y, 0.f);
    dfs[r][c4 + 2] = fmaxf(di * (gv.z + om * uv.z) + bv.z, 0.f);
    dfs[r][c4 + 3] = fmaxf(di * (gv.w + om * uv.w) + bv.w, 0.f);
    __syncthreads();
    int c = t & 15;
    float accv = 0.f;
#pragma unroll
    for (int k = 0; k < 64; k++) accv += dfs[r][k] * W4s[k * 16 + c];
    o[row * 16 + c] = di * accv;
}

__global__ void k_fixup2(const float* g0, const float* t0, const float* adj0, const float* d0, float* C0, long n0,
                         const float* g1, const float* t1, const float* adj1, const float* d1, float* C1, long n1,
                         const float* bias, int cols) {
    long idx = (long)blockIdx.x * 256 + threadIdx.x;
    long s0 = n0 * cols;
    const float* g; const float* tt; const float* adj; const float* dv; float* C; long n, li;
    if (idx < s0) { g = g0; tt = t0; adj = adj0; dv = d0; C = C0; n = n0; li = idx; }
    else {
        li = idx - s0;
        if (li >= n1 * cols) return;
        g = g1; tt = t1; adj = adj1; dv = d1; C = C1; n = n1;
    }
    long i = li / cols; int j = li % cols;
    float v = dv[i] * (g[li] + (1.0f - adj[i * n + i]) * tt[li]) + bias[j];
    C[li] = fmaxf(v, 0.f);
}

__global__ void k_adj16(const float* adj0, const float* u0, float* C0, int n0, int KS0, int Kc0,
                        const float* adj1, const float* u1, float* C1, int n1, int KS1, int Kc1) {
    int z = blockIdx.z;
    const float* adj; const float* u; float* C; int n, kz, Kc;
    if (z < KS0) { adj = adj0; u = u0; C = C0; n = n0; kz = z; Kc = Kc0; }
    else { adj = adj1; u = u1; C = C1; n = n1; kz = z - KS0; Kc = Kc1; }
    int r0 = blockIdx.x * 16;
    if (r0 >= n) return;
    int t = threadIdx.x;
    int r = r0 + (t >> 4), c = t & 15;
    int kb = kz * Kc, ke = min(n, kb + Kc);
    const float* arp = adj + (long)r * n;
    float acc = 0.f;
    for (int k = kb; k < ke; k += 4) {
        float4 a = *(const float4*)(arp + k);
        acc += a.x * u[(k + 0) * 16 + c] + a.y * u[(k + 1) * 16 + c]
             + a.z * u[(k + 2) * 16 + c] + a.w * u[(k + 3) * 16 + c];
    }
    atomicAdd(&C[r * 16 + c], acc);
}

// ---------------- stable top-K selection ----------------
__global__ void k_select(const float* __restrict__ cs, int* __restrict__ sel) {
    __shared__ float kk[240];
    int t = threadIdx.x;
    int b0 = blockIdx.x * 4;
    if (t < 240) kk[t] = cs[((long)(b0 * 60 + t)) * 64 + 63];
    __syncthreads();
    if (t < 240) {
        int lb = t / 60, i = t % 60;
        float key = kk[lb * 60 + i];
        int r = 0;
        for (int j = 0; j < 60; j++) {
            float kj = kk[lb * 60 + j];
            r += (kj > key) || (kj == key && j < i);
        }
        if (r < KSEL) sel[(b0 + lb) * KSEL + r] = (b0 + lb) * 60 + i;
    }
}

// ---------------- conv1 + relu + maxpool2 -> bf16 pool ----------------
// 8 batches per block: weights staged once (conflict-free linear layout, 2048 float4),
// xs double-buffered with register prefetch, pooled tile flushed as 240 contiguous uint4.
__global__ __launch_bounds__(256) void k_conv1_pool(const float* __restrict__ cs, const int* __restrict__ sel,
                                                    const float* __restrict__ c1w, const float* __restrict__ c1b,
                                                    ushort_t* __restrict__ po16) {
    __shared__ float4 w4lin[2048];      // w4lin[(tt4*4+j)*32+g] = c1w[(g*4+j)*64 + tt4*4 ..]
    __shared__ float4 xs4[2][480];      // xs4[buf][i*16+q]
    __shared__ ushort_t po[1920];
    __shared__ int sel_s[240];
    int t = threadIdx.x;
    int b0 = blockIdx.x * 8;
    for (int idx = t; idx < 2048; idx += 256) {
        int tt4 = idx >> 7, j = (idx >> 5) & 3, g2 = idx & 31;
        w4lin[idx] = *(const float4*)(c1w + (g2 * 4 + j) * 64 + tt4 * 4);
    }
    if (t < 240) sel_s[t] = sel[b0 * KSEL + t];
    __syncthreads();
    int g = t & 31, kq = t >> 5, k0 = kq * 4;
    int nk = (kq < 7) ? 4 : 2;
    float bb0 = c1b[g * 4], bb1 = c1b[g * 4 + 1], bb2 = c1b[g * 4 + 2], bb3 = c1b[g * 4 + 3];
    // preload batch 0
    float4 r0v, r1v = {0, 0, 0, 0};
    {
        int i0 = t >> 4, q0 = t & 15;
        r0v = ((const float4*)(cs + (long)sel_s[i0] * 64))[q0];
        if (t < 224) {
            int i1 = (256 + t) >> 4, q1 = t & 15;
            r1v = ((const float4*)(cs + (long)sel_s[i1] * 64))[q1];
        }
    }
    for (int ib = 0; ib < 8; ib++) {
        int cur = ib & 1;
        xs4[cur][t] = r0v;
        if (t < 224) xs4[cur][256 + t] = r1v;
        __syncthreads();
        // prefetch next batch while computing this one
        if (ib < 7) {
            int sbase = (ib + 1) * KSEL;
            int i0 = t >> 4, q0 = t & 15;
            r0v = ((const float4*)(cs + (long)sel_s[sbase + i0] * 64))[q0];
            if (t < 224) {
                int i1 = (256 + t) >> 4, q1 = t & 15;
                r1v = ((const float4*)(cs + (long)sel_s[sbase + i1] * 64))[q1];
            }
        }
        float acc[4][4] = {};
        for (int tt4 = 0; tt4 < 16; tt4++) {
            float4 wv0 = w4lin[(tt4 * 4 + 0) * 32 + g];
            float4 wv1 = w4lin[(tt4 * 4 + 1) * 32 + g];
            float4 wv2 = w4lin[(tt4 * 4 + 2) * 32 + g];
            float4 wv3 = w4lin[(tt4 * 4 + 3) * 32 + g];
#pragma unroll
            for (int k = 0; k < 4; k++) {
                if (k < nk) {
                    float4 xv = xs4[cur][(k0 + k) * 16 + tt4];
                    acc[k][0] += wv0.x * xv.x + wv0.y * xv.y + wv0.z * xv.z + wv0.w * xv.w;
                    acc[k][1] += wv1.x * xv.x + wv1.y * xv.y + wv1.z * xv.z + wv1.w * xv.w;
                    acc[k][2] += wv2.x * xv.x + wv2.y * xv.y + wv2.z * xv.z + wv2.w * xv.w;
                    acc[k][3] += wv3.x * xv.x + wv3.y * xv.y + wv3.z * xv.z + wv3.w * xv.w;
                }
            }
        }
        int npair = nk >> 1;
        for (int kp = 0; kp < npair; kp++) {
            int k2 = (k0 >> 1) + kp;
            float v00 = fmaxf(acc[2 * kp][0] + bb0, 0.f), v10 = fmaxf(acc[2 * kp + 1][0] + bb0, 0.f);
            float v01 = fmaxf(acc[2 * kp][1] + bb1, 0.f), v11 = fmaxf(acc[2 * kp + 1][1] + bb1, 0.f);
            float v02 = fmaxf(acc[2 * kp][2] + bb2, 0.f), v12 = fmaxf(acc[2 * kp + 1][2] + bb2, 0.f);
            float v03 = fmaxf(acc[2 * kp][3] + bb3, 0.f), v13 = fmaxf(acc[2 * kp + 1][3] + bb3, 0.f);
            po[k2 * 128 + g * 4 + 0] = f2bf(fmaxf(v00, v10));
            po[k2 * 128 + g * 4 + 1] = f2bf(fmaxf(v01, v11));
            po[k2 * 128 + g * 4 + 2] = f2bf(fmaxf(v02, v12));
            po[k2 * 128 + g * 4 + 3] = f2bf(fmaxf(v03, v13));
        }
        __syncthreads();
        // 240 x uint4 = full 1920-ushort tile (R8 bug: was 120 -> half tile poisoned)
        if (t < 240) ((uint4*)(po16 + (long)(b0 + ib) * 1920))[t] = ((const uint4*)po)[t];
        // next iteration's first barrier protects po and the other xs buffer
    }
}

// ---------------- weight prep (bf16, transposed [out][k]) ----------------
__global__ void k_w2colT(const float* __restrict__ c2w, ushort_t* __restrict__ o) {
    int idx = blockIdx.x * blockDim.x + threadIdx.x;
    if (idx >= 256 * 640) return;
    int oc = idx / 640, q = idx % 640;
    int tap = q >> 7, ic = q & 127;
    o[idx] = f2bf(c2w[(oc * 128 + ic) * 5 + tap]);
}

__global__ void k_w1pT(const float* __restrict__ w, ushort_t* __restrict__ o) {
    int idx = blockIdx.x * blockDim.x + threadIdx.x;
    if (idx >= 128 * 2816) return;
    int j = idx / 2816, c = idx % 2816;
    int tt = c >> 8, oc = c & 255;
    o[idx] = f2bf(w[(oc * 11 + tt) * 128 + j]);
}

// ---------------- lin2 + bn (lin1 bias + relu folded into load) ----------------
__global__ void k_lin2_bn(const float* __restrict__ x, const float* __restrict__ l1b,
                          const float* __restrict__ w,
                          const float* __restrict__ b, const float* __restrict__ g,
                          const float* __restrict__ bb, float* __restrict__ o) {
    int t = blockIdx.x * blockDim.x + threadIdx.x;
    int j = t & 31, bi = t >> 5;
    const float* xr = x + (long)bi * 128;
    float acc = b[j];
    for (int k = 0; k < 128; k++) acc += fmaxf(xr[k] + l1b[k], 0.f) * w[k * 32 + j];
    o[bi * 32 + j] = fmaxf(acc * g[j] + bb[j], 0.f);
}

// ---------------- final fused MLP ----------------
__global__ __launch_bounds__(256) void k_final(const float* __restrict__ hfin, const int* __restrict__ node,
                                               const float* __restrict__ dio, const float* __restrict__ dro,
                                               const float* __restrict__ pp,
                                               const float* __restrict__ fw, const float* __restrict__ fb,
                                               const float* __restrict__ f2w, const float* __restrict__ f2b,
                                               float* __restrict__ out) {
    __shared__ float w[64 * 32];
    __shared__ float w2[32];
    int t = threadIdx.x;
    for (int f = t; f < 2048; f += 256) w[f] = fw[f];
    if (t < 32) w2[t] = f2w[t];
    __syncthreads();
    int b = blockIdx.x * 256 + t;
    float p = *pp, q = 1.0f - p;
    float zin[64];
#pragma unroll
    for (int i = 0; i < 32; i++) zin[i] = hfin[b * 32 + i] * p;
    int n0 = node[b * 2], n1 = node[b * 2 + 1];
#pragma unroll
    for (int i = 0; i < 16; i++) zin[32 + i] = dio[n0 * 16 + i] * q;
#pragma unroll
    for (int i = 0; i < 16; i++) zin[48 + i] = dro[n1 * 16 + i] * q;
    float res = f2b[0];
    for (int j = 0; j < 32; j++) {
        float acc = fb[j];
#pragma unroll
        for (int i = 0; i < 64; i++) acc += zin[i] * w[i * 32 + j];
        res += fmaxf(acc, 0.f) * w2[j];
    }
    out[b] = res;
}

// ---------------- host ----------------
extern "C" void kernel_launch(void* const* d_in, const int* in_sizes, int n_in,
                              void* d_out, int out_size, void* d_ws, size_t ws_size,
                              hipStream_t stream) {
    const float* x        = (const float*)d_in[0];
    const int*   ei       = (const int*)d_in[1];
    const int*   node     = (const int*)d_in[3];
    const float* di_sim   = (const float*)d_in[4];
    const float* dr_sim   = (const float*)d_in[5];
    const float* drug_adj = (const float*)d_in[6];
    const float* dis_adj  = (const float*)d_in[7];
    const float* p        = (const float*)d_in[8];
    const float* W1 = (const float*)d_in[9],  *b1 = (const float*)d_in[10];
    const float* W2 = (const float*)d_in[11], *b2 = (const float*)d_in[12];
    const float* W3 = (const float*)d_in[13], *b3 = (const float*)d_in[14];
    const float* W4 = (const float*)d_in[15], *b4 = (const float*)d_in[16];
    const float* lin_di_w = (const float*)d_in[17], *lin_di_b = (const float*)d_in[18];
    const float* lin_dr_w = (const float*)d_in[19], *lin_dr_b = (const float*)d_in[20];
    const float* c1w = (const float*)d_in[21], *c1b = (const float*)d_in[22];
    const float* c2w = (const float*)d_in[23], *c2b = (const float*)d_in[24];
    const float* lin1w = (const float*)d_in[25], *lin1b = (const float*)d_in[26];
    const float* lin2w = (const float*)d_in[27], *lin2b = (const float*)d_in[28];
    const float* bng = (const float*)d_in[29], *bnb = (const float*)d_in[30];
    const float* fcsw = (const float*)d_in[31], *fcsb = (const float*)d_in[32];
    const float* fcs2w = (const float*)d_in[33], *fcs2b = (const float*)d_in[34];

    char* ws = (char*)d_ws;
    size_t o = 0;
    auto alloc = [&](size_t bytes) { size_t r = o; o += (bytes + 255) & ~(size_t)255; return r; };
    int*   csr     = (int*)(ws + alloc((size_t)NE * 4));
    int*   rowp    = (int*)(ws + alloc((size_t)NN * 4));
    int*   degcnt  = (int*)(ws + alloc((size_t)NN * 4));
    float* dinvn   = (float*)(ws + alloc((size_t)NN * 4));
    float* hbuf    = (float*)(ws + alloc((size_t)NN * 32 * 4));  // reused as pool16
    float* cs      = (float*)(ws + alloc((size_t)NN * 64 * 4));  // first 8MB reused as pairs; later act2
    int*   sel     = (int*)(ws + alloc((size_t)NB * KSEL * 4));
    float* hfin    = (float*)(ws + alloc((size_t)NB * 32 * 4));
    ushort_t* w2colT = (ushort_t*)(ws + alloc((size_t)256 * 640 * 2));
    ushort_t* w1pT   = (ushort_t*)(ws + alloc((size_t)128 * 2816 * 2));
    int*   bofs    = (int*)(ws + alloc((size_t)NBKT * 4));
    float* ddin_di = (float*)(ws + alloc((size_t)NDRUG * 4));
    float* ddin_dr = (float*)(ws + alloc((size_t)NDIS * 4));
    float* dt2_di  = (float*)(ws + alloc((size_t)NDRUG * 16 * 4));
    float* dt2_dr  = (float*)(ws + alloc((size_t)NDIS * 16 * 4));
    float* do_di   = (float*)(ws + alloc((size_t)NDRUG * 16 * 4));
    float* do_dr   = (float*)(ws + alloc((size_t)NDIS * 16 * 4));
    size_t zbase = o;
    int*   bcnt    = (int*)(ws + alloc((size_t)NBKT * 4));
    int*   bfill   = (int*)(ws + alloc((size_t)NBKT * 4));
    float* lin1o   = (float*)(ws + alloc((size_t)NB * 128 * 4));
    float* de_di   = (float*)(ws + alloc((size_t)NDRUG * 256 * 4));
    float* de_dr   = (float*)(ws + alloc((size_t)NDIS * 256 * 4));
    float* dt_di   = (float*)(ws + alloc((size_t)NDRUG * 64 * 4));
    float* dt_dr   = (float*)(ws + alloc((size_t)NDIS * 64 * 4));
    float* dg_di   = (float*)(ws + alloc((size_t)NDRUG * 64 * 4));
    float* dg_dr   = (float*)(ws + alloc((size_t)NDIS * 64 * 4));
    float* dg2_di  = (float*)(ws + alloc((size_t)NDRUG * 16 * 4));
    float* dg2_dr  = (float*)(ws + alloc((size_t)NDIS * 16 * 4));
    size_t zsize = o - zbase;
    uint_t* pairsg   = (uint_t*)cs;       // 8MB scratch, dead before cs is written
    ushort_t* pool16 = (ushort_t*)hbuf;   // alias after GCN done
    ushort_t* act2   = (ushort_t*)cs;     // alias after conv1 done

    hipMemsetAsync(ws + zbase, 0, zsize, stream);

    // CSR build: bucketed 2-pass sort
    k_bcount<<<512, 256, 0, stream>>>(ei, bcnt);
    k_bscan<<<1, 512, 0, stream>>>(bcnt, bofs);
    k_bscatter<<<(NE + CHUNK - 1) / CHUNK, 256, 0, stream>>>(ei, bofs, bfill, pairsg);
    k_bbuild<<<NBKT, 256, 0, stream>>>(pairsg, bofs, bcnt, csr, rowp, degcnt, dinvn);

    // GCN (fp32 — preserves stable sort keys)
    k_xw<<<NN / 64, 256, 0, stream>>>(x, W1, hbuf, 64, 64);
    k_gcn_agg<<<NN / 32, 256, 0, stream>>>(hbuf, csr, rowp, degcnt, dinvn, b1, cs, 0);
    k_xw<<<NN / 64, 256, 0, stream>>>(cs, W2, hbuf, 32, 64);
    k_gcn_agg<<<NN / 32, 256, 0, stream>>>(hbuf, csr, rowp, degcnt, dinvn, b2, cs, 32);

    k_select<<<NB / 4, 256, 0, stream>>>(cs, sel);

    // weight prep (bf16 transposed)
    k_w2colT<<<(256 * 640 + 255) / 256, 256, 0, stream>>>(c2w, w2colT);
    k_w1pT<<<(128 * 2816 + 255) / 256, 256, 0, stream>>>(lin1w, w1pT);

    // conv1 + pool -> bf16 pool16 (aliases hbuf); 8 batches/block
    k_conv1_pool<<<NB / 8, 256, 0, stream>>>(cs, sel, c1w, c1b, pool16);

    // conv2: bf16 MFMA -> act2 bf16 (aliases cs)
    k_conv2_mfma<<<dim3(352, 2), 256, 0, stream>>>(pool16, w2colT, act2, c2b);

    // lin1: bf16 MFMA split-K -> lin1o fp32 (zeroed)
    k_lin1_mfma<<<dim3(32, 1, 4), 256, 0, stream>>>(act2, w1pT, lin1o);
    k_lin2_bn<<<NB * 32 / 256, 256, 0, stream>>>(lin1o, lin1b, lin2w, lin2b, bng, bnb, hfin);

    // ---- dense drug (p0) + disease (p1) paths (fp32) ----
    k_dense_deg2<<<(NDRUG + NDIS) * 64 / 256, 256, 0, stream>>>(drug_adj, ddin_di, NDRUG, dis_adj, ddin_dr, NDIS);
    k_gemm_sk<<<dim3(NDIS / 64, 4, 12), 256, 0, stream>>>(
        di_sim, lin_di_w, de_di, nullptr, nullptr, NDRUG, 256, NDRUG, NDRUG, 4, 256,
        dr_sim, lin_dr_w, de_dr, nullptr, nullptr, NDIS, 256, NDIS, NDIS, 8, 256);
    k_gemm_sk<<<dim3(NDIS / 64, 1, 8), 256, 0, stream>>>(
        de_di, W3, dt_di, lin_di_b, ddin_di, NDRUG, 64, 256, 256, 4, 64,
        de_dr, W3, dt_dr, lin_dr_b, ddin_dr, NDIS, 64, 256, 256, 4, 64);
    k_gemm_sk<<<dim3(NDIS / 64, 1, 24), 256, 0, stream>>>(
        drug_adj, dt_di, dg_di, nullptr, nullptr, NDRUG, 64, NDRUG, NDRUG, 8, 128,
        dis_adj, dt_dr, dg_dr, nullptr, nullptr, NDIS, 64, NDIS, NDIS, 16, 128);
    k_fix_w4<<<(NDRUG + NDIS) / 16, 256, 0, stream>>>(
        dg_di, dt_di, drug_adj, ddin_di, dt2_di, NDRUG,
        dg_dr, dt_dr, dis_adj, ddin_dr, dt2_dr, NDIS, b3, W4);
    k_adj16<<<dim3(NDIS / 16, 1, 6), 256, 0, stream>>>(
        drug_adj, dt2_di, dg2_di, NDRUG, 2, 512,
        dis_adj, dt2_dr, dg2_dr, NDIS, 4, 512);
    k_fixup2<<<((NDRUG + NDIS) * 16 + 255) / 256, 256, 0, stream>>>(
        dg2_di, dt2_di, drug_adj, ddin_di, do_di, NDRUG,
        dg2_dr, dt2_dr, dis_adj, ddin_dr, do_dr, NDIS, b4, 16);

    k_final<<<NB / 256, 256, 0, stream>>>(hfin, node, do_di, do_dr, p, fcsw, fcsb, fcs2w, fcs2b, (float*)d_out);
}